// Round 3
// baseline (491.674 us; speedup 1.0000x reference)
//
#include <hip/hip_runtime.h>

// DIAGNOSTIC PROBE ROUND — same math as Round 2 (verified, absmax 0.00195),
// but the store phase is repeated `reps` times (runtime-opaque, idempotent)
// so the kernel dispatch becomes long enough to appear in rocprof top-5 and
// yield direct counters (hbm_gbps / VALUBusy / WRITE_SIZE) for the store path.
//
// out[h1,w1,c1,h2,w2,c2] = gamma^(|h1-h2|+|w1-w2|) * E[c1][c2]
// E[c1][c2] = gamma^|c1-c2| * decay[c1] * (1 + spec_pe[c1,c2]*m(h1,w1,c1))
// m = Sh[h1]*Sh[w1]*meanC[c1]

typedef float f32x4 __attribute__((ext_vector_type(4)));

__global__ __launch_bounds__(256) void manhattan_relpos_kernel(
    const float* __restrict__ decay,    // 8 elems
    const float* __restrict__ spec_pe,  // 64 elems
    float* __restrict__ out,            // 67108864 floats
    int reps,                           // 6 (runtime-opaque)
    int zoff)                           // 0 (runtime-opaque, defeats DSE)
{
    __shared__ float powtab[72];
    __shared__ float P2d[1024];
    __shared__ float E[64];
    __shared__ float mC[8];
    __shared__ float Ssum[2];

    const int tid = threadIdx.x;
    const int h1 = blockIdx.x >> 5;
    const int w1 = blockIdx.x & 31;

    if (tid < 72)
        powtab[tid] = exp2f((float)tid * -0.15200309344504997f);
    __syncthreads();

    #pragma unroll
    for (int k = 0; k < 4; ++k) {
        const int i  = tid + (k << 8);
        const int h2 = i >> 5, w2 = i & 31;
        P2d[i] = powtab[abs(h1 - h2) + abs(w1 - w2)];
    }
    if (tid < 2) {
        const int a = tid ? w1 : h1;
        float s = 0.0f;
        #pragma unroll
        for (int j = 0; j < 32; ++j) s += powtab[abs(a - j)];
        Ssum[tid] = s;
    } else if (tid >= 8 && tid < 16) {
        const int c1 = tid - 8;
        float s = 0.0f;
        #pragma unroll
        for (int j = 0; j < 8; ++j) s += powtab[abs(c1 - j)];
        mC[c1] = s * (1.0f / 8192.0f);
    }
    __syncthreads();

    if (tid < 64) {
        const int c1 = tid >> 3, c2 = tid & 7;
        const float m = Ssum[0] * Ssum[1] * mC[c1];
        E[tid] = powtab[abs(c1 - c2)] * decay[c1] * fmaf(spec_pe[tid], m, 1.0f);
    }
    __syncthreads();

    const int half  = tid & 1;
    const int pbase = ((tid >> 6) << 5) + ((tid >> 1) & 31);
    f32x4* out4 = reinterpret_cast<f32x4*>(out) + ((size_t)blockIdx.x << 14) + tid;
    const f32x4* E4 = reinterpret_cast<const f32x4*>(E);

    float pr[8];
    #pragma unroll
    for (int hh = 0; hh < 8; ++hh) pr[hh] = P2d[pbase + (hh << 7)];

    for (int r = 0; r < reps; ++r) {
        f32x4* o = out4 + (size_t)r * (size_t)zoff;  // zoff==0: same addrs, opaque to DSE
        #pragma unroll
        for (int c1 = 0; c1 < 8; ++c1) {
            const f32x4 e = E4[(c1 << 1) + half];
            #pragma unroll
            for (int hh = 0; hh < 8; ++hh) {
                const f32x4 v = pr[hh] * e;
                __builtin_nontemporal_store(v, o + (c1 << 11) + (hh << 8));
            }
        }
    }
}

extern "C" void kernel_launch(void* const* d_in, const int* in_sizes, int n_in,
                              void* d_out, int out_size, void* d_ws, size_t ws_size,
                              hipStream_t stream) {
    const float* decay   = (const float*)d_in[1];
    const float* spec_pe = (const float*)d_in[2];
    float* out = (float*)d_out;

    dim3 grid(1024), block(256);
    manhattan_relpos_kernel<<<grid, block, 0, stream>>>(decay, spec_pe, out,
                                                        /*reps=*/6, /*zoff=*/0);
}

// Round 4
// 255.405 us; speedup vs baseline: 1.9251x; 1.9251x over previous
//
#include <hip/hip_runtime.h>

// out[h1,w1,c1,h2,w2,c2] = gamma^(|h1-h2|+|w1-w2|) * E[c1][c2]
// E[c1][c2] = gamma^|c1-c2| * decay[c1] * (1 + spec_pe[c1,c2]*m(h1,w1,c1))
// m = Sh[h1]*Sh[w1]*meanC[c1]
//
// H=W=32, C=8. One block per (h1,w1): writes a contiguous 65536-float
// (256 KiB) tile. Inner loop = P2d (registers) x E (float4) -> pure stores.
// Grid 1024 x 256 threads = 4 blocks/CU (16 waves/CU).
//
// Round-3 probe established: store phase is pure write-bound (VALUBusy 2.6%,
// FETCH~0, WRITE_SIZE = full passes). Plain stores (not nontemporal): the
// harness fill achieves 6.3-6.7 TB/s with plain streaming stores while nt
// sustained only 5.3-5.9 TB/s in the 6-rep probe.

typedef float f32x4 __attribute__((ext_vector_type(4)));

__global__ __launch_bounds__(256) void manhattan_relpos_kernel(
    const float* __restrict__ decay,    // 8 elems
    const float* __restrict__ spec_pe,  // 64 elems
    float* __restrict__ out)            // 67108864 floats
{
    __shared__ float powtab[72];   // gamma^d
    __shared__ float P2d[1024];    // [h2][w2] = gamma^(|h1-h2|+|w1-w2|)
    __shared__ float E[64];        // [c1][c2] fused c-term
    __shared__ float mC[8];        // (sum_c2 gamma^|c1-c2|)/8192
    __shared__ float Ssum[2];      // Sh[h1], Sh[w1]

    const int tid = threadIdx.x;
    const int h1 = blockIdx.x >> 5;
    const int w1 = blockIdx.x & 31;

    // gamma^d table; log2(0.9) = -0.15200309344504997 (same numerics as baseline)
    if (tid < 72)
        powtab[tid] = exp2f((float)tid * -0.15200309344504997f);
    __syncthreads();

    #pragma unroll
    for (int k = 0; k < 4; ++k) {
        const int i  = tid + (k << 8);
        const int h2 = i >> 5, w2 = i & 31;
        P2d[i] = powtab[abs(h1 - h2) + abs(w1 - w2)];
    }
    if (tid < 2) {
        const int a = tid ? w1 : h1;
        float s = 0.0f;
        #pragma unroll
        for (int j = 0; j < 32; ++j) s += powtab[abs(a - j)];
        Ssum[tid] = s;
    } else if (tid >= 8 && tid < 16) {
        const int c1 = tid - 8;
        float s = 0.0f;
        #pragma unroll
        for (int j = 0; j < 8; ++j) s += powtab[abs(c1 - j)];
        mC[c1] = s * (1.0f / 8192.0f);
    }
    __syncthreads();

    if (tid < 64) {
        const int c1 = tid >> 3, c2 = tid & 7;
        const float m = Ssum[0] * Ssum[1] * mC[c1];
        E[tid] = powtab[abs(c1 - c2)] * decay[c1] * fmaf(spec_pe[tid], m, 1.0f);
    }
    __syncthreads();

    // float4 tile index bits: 0 = c2-half, 1..5 = w2, 6..7 = h2-lo,
    // iteration supplies h2-hi (hh) and c1.
    const int half  = tid & 1;
    const int pbase = ((tid >> 6) << 5) + ((tid >> 1) & 31);  // h2lo*32 + w2
    f32x4* out4 = reinterpret_cast<f32x4*>(out) + ((size_t)blockIdx.x << 14) + tid;
    const f32x4* E4 = reinterpret_cast<const f32x4*>(E);

    // Hoist the 8 P2d values this thread ever needs into registers.
    float pr[8];
    #pragma unroll
    for (int hh = 0; hh < 8; ++hh) pr[hh] = P2d[pbase + (hh << 7)];

    #pragma unroll
    for (int c1 = 0; c1 < 8; ++c1) {
        const f32x4 e = E4[(c1 << 1) + half];
        #pragma unroll
        for (int hh = 0; hh < 8; ++hh) {
            out4[(c1 << 11) + (hh << 8)] = pr[hh] * e;
        }
    }
}

extern "C" void kernel_launch(void* const* d_in, const int* in_sizes, int n_in,
                              void* d_out, int out_size, void* d_ws, size_t ws_size,
                              hipStream_t stream) {
    // d_in[0] = x (unused by the math — only shape/dtype matter)
    const float* decay   = (const float*)d_in[1];
    const float* spec_pe = (const float*)d_in[2];
    float* out = (float*)d_out;

    dim3 grid(1024), block(256);
    manhattan_relpos_kernel<<<grid, block, 0, stream>>>(decay, spec_pe, out);
}